// Round 8
// baseline (244.283 us; speedup 1.0000x reference)
//
#include <hip/hip_runtime.h>
#include <hip/hip_bf16.h>

#define BB 2
#define SS 2048
#define DD 1024
#define HH 16
#define DHD 64

typedef __attribute__((ext_vector_type(8))) short short8;   // 8 bf16 = 4 VGPRs
typedef __attribute__((ext_vector_type(4))) float floatx4;  // MFMA C/D

static __device__ __forceinline__ unsigned short f2bf(float f) {
    union { __hip_bfloat16 h; unsigned short u; } cv;
    cv.h = __float2bfloat16(f);
    return cv.u;
}

// ---------------------------------------------------------------------------
// Fused prep kernel. Block-uniform branch on blockIdx.x range; 4096 blocks.
//   [0,1024)    : residual passthrough (4 float4/thread — exactly B*S*D floats)
//   [1024,3072) : x fp32 -> bf16 (8 elems / thread)
//   [3072,3840) : W_{Q,K,V} [H][1024][64] -> Wt [3072][1024] bf16
//   [3840,4096) : W_O [1024k][1024n] -> WtO [1024n][1024k] bf16
// ---------------------------------------------------------------------------
__global__ __launch_bounds__(256) void prep(const float4* __restrict__ residual4,
        float4* __restrict__ out4,
        const float* __restrict__ x, unsigned short* __restrict__ xb,
        const float* __restrict__ WQ, const float* __restrict__ WK,
        const float* __restrict__ WV, unsigned short* __restrict__ Wt,
        const float* __restrict__ WO, unsigned short* __restrict__ WtO) {
    __shared__ float tile[64][65];
    const int bid = blockIdx.x;
    const int t = threadIdx.x;

    if (bid < 1024) {                              // residual copy
        size_t base = (size_t)bid * 1024 + t;
#pragma unroll
        for (int j = 0; j < 4; j++) out4[base + j * 256] = residual4[base + j * 256];
    } else if (bid < 3072) {                       // x -> bf16
        size_t i = ((size_t)(bid - 1024) * 256 + t) * 8;
        const float* src = x + i;
        short8 o;
#pragma unroll
        for (int j = 0; j < 8; j++) o[j] = (short)f2bf(src[j]);
        *(short8*)(xb + i) = o;
    } else if (bid < 3840) {                       // W_QKV transpose
        int u = bid - 3072;
        const int d0 = (u & 15) * 64;
        const int h  = (u >> 4) & 15;
        const int which = u >> 8;
        const float* W = (which == 0) ? WQ : (which == 1) ? WK : WV;
        const float* src = W + (size_t)h * DD * DHD;
#pragma unroll
        for (int i = 0; i < 16; i++) {
            int idx = i * 256 + t;
            int r = idx >> 6, c = idx & 63;
            tile[r][c] = src[(size_t)(d0 + r) * DHD + c];
        }
        __syncthreads();
        unsigned short* dst = Wt + ((size_t)which * 1024 + h * 64) * DD;
#pragma unroll
        for (int i = 0; i < 16; i++) {
            int idx = i * 256 + t;
            int e = idx >> 6, d = idx & 63;
            dst[(size_t)e * DD + d0 + d] = f2bf(tile[d][e]);
        }
    } else {                                       // W_O transpose
        int u = bid - 3840;
        const int k0 = (u & 15) * 64;
        const int n0 = (u >> 4) * 64;
#pragma unroll
        for (int i = 0; i < 16; i++) {
            int idx = i * 256 + t;
            int r = idx >> 6, c = idx & 63;
            tile[r][c] = WO[(size_t)(k0 + r) * DD + n0 + c];
        }
        __syncthreads();
#pragma unroll
        for (int i = 0; i < 16; i++) {
            int idx = i * 256 + t;
            int n = idx >> 6, kk = idx & 63;
            WtO[(size_t)(n0 + n) * DD + k0 + kk] = f2bf(tile[kk][n]);
        }
    }
}

// ---------------------------------------------------------------------------
// QKV MFMA GEMM, padded-stride staging. grid (32, 24); block 256 = 4 waves.
// Q/K written [B][H][S][64]; V written PRE-TRANSPOSED [B][H][64][S] so attn
// can stage V^T tiles with b128 reads+writes (kills the b16 LDS scatter).
// V's 2B stores hit 4KB-strided lines, but each 128B line is fully covered
// within this block -> L2 write-combines to 8.4 MB total.
// ---------------------------------------------------------------------------
#define GSTRIDE 72
__global__ __launch_bounds__(256) void qkv_mfma(const unsigned short* __restrict__ xb,
        const unsigned short* __restrict__ Wt,
        const float* __restrict__ bQ, const float* __restrict__ bK,
        const float* __restrict__ bV,
        unsigned short* __restrict__ oq, unsigned short* __restrict__ ok,
        unsigned short* __restrict__ ov) {
    __shared__ unsigned short As[128 * GSTRIDE];
    __shared__ unsigned short Bs[128 * GSTRIDE];

    const int m0 = blockIdx.x * 128;
    const int y  = blockIdx.y;
    const int which = y >> 3;
    const int h0 = (y & 7) * 2;
    const float* bias = (which == 0) ? bQ : (which == 1) ? bK : bV;
    unsigned short* ob = (which == 0) ? oq : (which == 1) ? ok : ov;
    const float scale = (which == 0) ? 0.125f : 1.0f;
    const unsigned short* Wb = Wt + (size_t)y * 128 * DD;

    const int t = threadIdx.x;
    const int lane = t & 63, w = t >> 6;
    const int l15 = lane & 15, quad = lane >> 4;

    floatx4 acc[2][8];
#pragma unroll
    for (int mt = 0; mt < 2; mt++)
#pragma unroll
        for (int nt = 0; nt < 8; nt++) acc[mt][nt] = floatx4{0.f, 0.f, 0.f, 0.f};

    for (int k0 = 0; k0 < DD; k0 += 64) {
#pragma unroll
        for (int i = 0; i < 4; i++) {
            int idx = i * 256 + t;
            int row = idx >> 3, c8 = idx & 7;
            *(short8*)(As + row * GSTRIDE + c8 * 8) =
                *(const short8*)(xb + (size_t)(m0 + row) * DD + k0 + c8 * 8);
        }
#pragma unroll
        for (int i = 0; i < 4; i++) {
            int idx = i * 256 + t;
            int row = idx >> 3, c8 = idx & 7;
            *(short8*)(Bs + row * GSTRIDE + c8 * 8) =
                *(const short8*)(Wb + (size_t)row * DD + k0 + c8 * 8);
        }
        __syncthreads();
#pragma unroll
        for (int ks = 0; ks < 2; ks++) {
            short8 af[2], bf[8];
#pragma unroll
            for (int mt = 0; mt < 2; mt++)
                af[mt] = *(const short8*)(As + (w * 32 + mt * 16 + l15) * GSTRIDE +
                                          ks * 32 + quad * 8);
#pragma unroll
            for (int nt = 0; nt < 8; nt++)
                bf[nt] = *(const short8*)(Bs + (nt * 16 + l15) * GSTRIDE +
                                          ks * 32 + quad * 8);
#pragma unroll
            for (int mt = 0; mt < 2; mt++)
#pragma unroll
                for (int nt = 0; nt < 8; nt++)
                    acc[mt][nt] = __builtin_amdgcn_mfma_f32_16x16x32_bf16(
                        af[mt], bf[nt], acc[mt][nt], 0, 0, 0);
        }
        __syncthreads();
    }
#pragma unroll
    for (int mt = 0; mt < 2; mt++) {
#pragma unroll
        for (int r = 0; r < 4; r++) {
            int m = m0 + w * 32 + mt * 16 + quad * 4 + r;
            int b = m >> 11, s = m & (SS - 1);
#pragma unroll
            for (int nt = 0; nt < 8; nt++) {
                int h = h0 + (nt >> 2);
                int e = (nt & 3) * 16 + l15;
                float v = (acc[mt][nt][r] + bias[h * DHD + e]) * scale;
                if (which == 2)                     // V: [B][H][64][S]
                    ob[(((size_t)b * HH + h) * DHD + e) * SS + s] = f2bf(v);
                else                                // Q,K: [B][H][S][64]
                    ob[(((size_t)b * HH + h) * SS + s) * DHD + e] = f2bf(v);
            }
        }
    }
}

// ---------------------------------------------------------------------------
// MFMA flash attention, no-rescale softmax. Q-tile 128, K-tile 128 (half the
// barriers of round 7; per-16-frag causal skip unchanged so ~no extra MFMA).
// block = 512 threads = 8 waves; wave w owns q rows [q0+w*16, q0+w*16+16).
// V arrives pre-transposed [B][H][64][S]: Vt staged b128->b128, no scatter.
// LDS 69 KB -> 2 blocks/CU = 16 waves/CU.
// grid 512: i<256 heavy (qt=15-(i>>5)) first; i and i+256 same CU under
// round-robin -> per-CU pair work constant (17 tiles).
// ---------------------------------------------------------------------------
#define KSTRIDE 72    // Ks row stride (halfwords); 9x16B, odd -> b128-clean
#define VSTRIDE 136   // Vt/Ps row stride (halfwords); 17x16B, odd -> b128-clean
__global__ __launch_bounds__(512) void attn(const unsigned short* __restrict__ q,
        const unsigned short* __restrict__ k, const unsigned short* __restrict__ vt,
        unsigned short* __restrict__ z) {
    __shared__ unsigned short Ks[128 * KSTRIDE];
    __shared__ unsigned short Vt[64 * VSTRIDE];
    __shared__ unsigned short Ps[8 * 16 * VSTRIDE];

    const int i0 = blockIdx.x;
    int bh, qt;
    if (i0 < 256) { bh = i0 & 31;         qt = 15 - (i0 >> 5); }
    else          { bh = (i0 - 256) & 31; qt = (i0 - 256) >> 5; }
    const int b  = bh >> 4, h = bh & (HH - 1);
    const int q0 = qt * 128;

    const int t = threadIdx.x;
    const int lane = t & 63;
    const int w = t >> 6;                          // 0..7
    const int l15 = lane & 15;
    const int quad = lane >> 4;

    const unsigned short* qb  = q  + (size_t)bh * SS * DHD;
    const unsigned short* kb  = k  + (size_t)bh * SS * DHD;
    const unsigned short* vtb = vt + (size_t)bh * DHD * SS;   // [e][s]

    // Q A-frag: rows q0 + w*16 + l15
    short8 a_frag[2];
#pragma unroll
    for (int c = 0; c < 2; c++)
        a_frag[c] = *(const short8*)(qb +
            (size_t)(q0 + w * 16 + l15) * DHD + c * 32 + quad * 8);

    float lsum[4];
    floatx4 o_acc[4];
#pragma unroll
    for (int r = 0; r < 4; r++) lsum[r] = 0.f;
#pragma unroll
    for (int nt = 0; nt < 4; nt++) o_acc[nt] = floatx4{0.f, 0.f, 0.f, 0.f};

    unsigned short* Psw = Ps + w * 16 * VSTRIDE;
    const int fmin = q0 + w * 16;
    const int wave_max_row = fmin + 15;
    const int nkt = qt + 1;                        // 128-wide k-tiles

    for (int kt = 0; kt < nkt; kt++) {
        __syncthreads();
#pragma unroll
        for (int i = 0; i < 2; i++) {              // stage K: 128 rows x 64e
            int u = i * 512 + t;
            int row = u >> 3, c8 = u & 7;
            *(short8*)(Ks + row * KSTRIDE + c8 * 8) =
                *(const short8*)(kb + (size_t)(kt * 128 + row) * DHD + c8 * 8);
        }
#pragma unroll
        for (int i = 0; i < 2; i++) {              // stage Vt: 64 e-rows x 128kp
            int u = i * 512 + t;
            int e = u >> 4, c8 = u & 15;
            *(short8*)(Vt + e * VSTRIDE + c8 * 8) =
                *(const short8*)(vtb + (size_t)e * SS + kt * 128 + c8 * 8);
        }
        __syncthreads();

        // S = Q K^T over 8 16-wide n-frags
        floatx4 sacc[8];
#pragma unroll
        for (int nt = 0; nt < 8; nt++) {
            const int kb0 = kt * 128 + nt * 16;
            if (kb0 > wave_max_row) {
                sacc[nt] = floatx4{-1e30f, -1e30f, -1e30f, -1e30f};
            } else {
                short8 bf0 = *(const short8*)(Ks + (nt * 16 + l15) * KSTRIDE +
                                              quad * 8);
                short8 bf1 = *(const short8*)(Ks + (nt * 16 + l15) * KSTRIDE +
                                              32 + quad * 8);
                floatx4 acc = {0.f, 0.f, 0.f, 0.f};
                acc = __builtin_amdgcn_mfma_f32_16x16x32_bf16(a_frag[0], bf0, acc,
                                                              0, 0, 0);
                acc = __builtin_amdgcn_mfma_f32_16x16x32_bf16(a_frag[1], bf1, acc,
                                                              0, 0, 0);
                if (kb0 + 15 > fmin) {             // diagonal straddle: mask
#pragma unroll
                    for (int r = 0; r < 4; r++)
                        if (kb0 + l15 > fmin + quad * 4 + r) acc[r] = -1e30f;
                }
                sacc[nt] = acc;
            }
        }

        // exp, partial row sums, P -> Ps (A-layout rows, 128 wide)
#pragma unroll
        for (int r = 0; r < 4; r++) {
            float ps = 0.f;
#pragma unroll
            for (int nt = 0; nt < 8; nt++) {
                float pv = __expf(sacc[nt][r]);
                ps += pv;
                Psw[(quad * 4 + r) * VSTRIDE + nt * 16 + l15] = f2bf(pv);
            }
            lsum[r] += ps;
        }

        // PV: A = P rows (k=128 in 4 steps), B = Vt
        short8 pa[4];
#pragma unroll
        for (int ks = 0; ks < 4; ks++)
            pa[ks] = *(const short8*)(Psw + l15 * VSTRIDE + ks * 32 + quad * 8);
#pragma unroll
        for (int nt = 0; nt < 4; nt++) {
#pragma unroll
            for (int ks = 0; ks < 4; ks++) {
                short8 bf = *(const short8*)(Vt + (nt * 16 + l15) * VSTRIDE +
                                             ks * 32 + quad * 8);
                o_acc[nt] = __builtin_amdgcn_mfma_f32_16x16x32_bf16(
                    pa[ks], bf, o_acc[nt], 0, 0, 0);
            }
        }
    }

    // final: reduce row sums across 16-lane group, normalize, store
#pragma unroll
    for (int r = 0; r < 4; r++) {
        float s = lsum[r];
#pragma unroll
        for (int off = 1; off < 16; off <<= 1) s += __shfl_xor(s, off);
        float inv = 1.f / s;
        int qrow = q0 + w * 16 + quad * 4 + r;
        unsigned short* zr = z + ((size_t)b * SS + qrow) * (HH * DHD) + h * DHD;
#pragma unroll
        for (int nt = 0; nt < 4; nt++)
            zr[nt * 16 + l15] = f2bf(o_acc[nt][r] * inv);
    }
}

// ---------------------------------------------------------------------------
// O-proj MFMA GEMM, 64x128 tiles. grid (64, 8) = 512 blocks (2/CU — round 7's
// (32,8)=1/CU was the occupancy-starved straggler). block 256 = 4 waves;
// wave w: rows [m0+w*16, m0+w*16+16) x 128 N.
// ---------------------------------------------------------------------------
__global__ __launch_bounds__(256) void out_mfma(const unsigned short* __restrict__ zb,
        const unsigned short* __restrict__ WtO, const float* __restrict__ bo,
        float* __restrict__ out) {
    __shared__ unsigned short As[64 * GSTRIDE];
    __shared__ unsigned short Bs[128 * GSTRIDE];

    const int m0 = blockIdx.x * 64;
    const int n0 = blockIdx.y * 128;
    const int t = threadIdx.x;
    const int lane = t & 63, w = t >> 6;
    const int l15 = lane & 15, quad = lane >> 4;

    floatx4 acc[8];
#pragma unroll
    for (int nt = 0; nt < 8; nt++) acc[nt] = floatx4{0.f, 0.f, 0.f, 0.f};

    for (int k0 = 0; k0 < DD; k0 += 64) {
#pragma unroll
        for (int i = 0; i < 2; i++) {              // stage A: 64 x 64
            int idx = i * 256 + t;
            int row = idx >> 3, c8 = idx & 7;
            *(short8*)(As + row * GSTRIDE + c8 * 8) =
                *(const short8*)(zb + (size_t)(m0 + row) * DD + k0 + c8 * 8);
        }
#pragma unroll
        for (int i = 0; i < 4; i++) {              // stage B: 128 x 64
            int idx = i * 256 + t;
            int row = idx >> 3, c8 = idx & 7;
            *(short8*)(Bs + row * GSTRIDE + c8 * 8) =
                *(const short8*)(WtO + (size_t)(n0 + row) * DD + k0 + c8 * 8);
        }
        __syncthreads();
#pragma unroll
        for (int ks = 0; ks < 2; ks++) {
            short8 af = *(const short8*)(As + (w * 16 + l15) * GSTRIDE +
                                         ks * 32 + quad * 8);
#pragma unroll
            for (int nt = 0; nt < 8; nt++) {
                short8 bf = *(const short8*)(Bs + (nt * 16 + l15) * GSTRIDE +
                                             ks * 32 + quad * 8);
                acc[nt] = __builtin_amdgcn_mfma_f32_16x16x32_bf16(
                    af, bf, acc[nt], 0, 0, 0);
            }
        }
        __syncthreads();
    }
#pragma unroll
    for (int r = 0; r < 4; r++) {
        int m = m0 + w * 16 + quad * 4 + r;
#pragma unroll
        for (int nt = 0; nt < 8; nt++) {
            int n = n0 + nt * 16 + l15;
            out[(size_t)m * DD + n] = acc[nt][r] + bo[n];
        }
    }
}

extern "C" void kernel_launch(void* const* d_in, const int* in_sizes, int n_in,
                              void* d_out, int out_size, void* d_ws, size_t ws_size,
                              hipStream_t stream) {
    const float* residual = (const float*)d_in[0];
    const float* x   = (const float*)d_in[1];
    const float* W_Q = (const float*)d_in[2];
    const float* W_K = (const float*)d_in[3];
    const float* W_V = (const float*)d_in[4];
    const float* W_O = (const float*)d_in[5];
    const float* b_Q = (const float*)d_in[6];
    const float* b_K = (const float*)d_in[7];
    const float* b_V = (const float*)d_in[8];
    const float* b_O = (const float*)d_in[9];
    float* out = (float*)d_out;

    const size_t NE = (size_t)BB * SS * HH * DHD;
    unsigned short* xb  = (unsigned short*)d_ws;
    unsigned short* Wt  = xb + (size_t)4096 * 1024;
    unsigned short* WtO = Wt + (size_t)3072 * 1024;
    unsigned short* qb  = WtO + (size_t)1024 * 1024;
    unsigned short* kb  = qb + NE;
    unsigned short* vb  = kb + NE;          // [B][H][64][S] (pre-transposed)
    unsigned short* zb  = vb + NE;

    prep<<<4096, 256, 0, stream>>>((const float4*)residual, (float4*)out,
                                   x, xb, W_Q, W_K, W_V, Wt, W_O, WtO);

    qkv_mfma<<<dim3(32, 24), 256, 0, stream>>>(xb, Wt, b_Q, b_K, b_V, qb, kb, vb);

    attn<<<512, 512, 0, stream>>>(qb, kb, vb, zb);

    out_mfma<<<dim3(64, 8), 256, 0, stream>>>(
        zb, WtO, b_O, out + (size_t)BB * SS * DD);
}

// Round 9
// 213.267 us; speedup vs baseline: 1.1454x; 1.1454x over previous
//
#include <hip/hip_runtime.h>
#include <hip/hip_bf16.h>

#define BB 2
#define SS 2048
#define DD 1024
#define HH 16
#define DHD 64

typedef __attribute__((ext_vector_type(8))) short short8;   // 8 bf16 = 4 VGPRs
typedef __attribute__((ext_vector_type(4))) float floatx4;  // MFMA C/D

static __device__ __forceinline__ unsigned short f2bf(float f) {
    union { __hip_bfloat16 h; unsigned short u; } cv;
    cv.h = __float2bfloat16(f);
    return cv.u;
}

// async global->LDS 16B copy; LDS dest MUST be wave-uniform base + lane*16
typedef __attribute__((address_space(1))) const unsigned int* gas_t;
typedef __attribute__((address_space(3))) unsigned int* las_t;
static __device__ __forceinline__ void g2l16(const void* g, void* l) {
    __builtin_amdgcn_global_load_lds((gas_t)g, (las_t)l, 16, 0, 0);
}

// XOR swizzle: LDS[row][c8] holds global[row][c8 ^ (row&7)] (c8 = 16B chunk).
// Unpadded stride-64hw rows stay g2l16-compatible; frag reads (16 rows per
// l15 group) land on 8 distinct chunks -> 32 banks / 8 lanes -> 2-way = free.
#define SW(row, c8) ((c8) ^ ((row) & 7))

// ---------------------------------------------------------------------------
// Fused prep kernel. Block-uniform branch on blockIdx.x range; 4096 blocks.
// ---------------------------------------------------------------------------
__global__ __launch_bounds__(256) void prep(const float4* __restrict__ residual4,
        float4* __restrict__ out4,
        const float* __restrict__ x, unsigned short* __restrict__ xb,
        const float* __restrict__ WQ, const float* __restrict__ WK,
        const float* __restrict__ WV, unsigned short* __restrict__ Wt,
        const float* __restrict__ WO, unsigned short* __restrict__ WtO) {
    __shared__ float tile[64][65];
    const int bid = blockIdx.x;
    const int t = threadIdx.x;

    if (bid < 1024) {                              // residual copy
        size_t base = (size_t)bid * 1024 + t;
#pragma unroll
        for (int j = 0; j < 4; j++) out4[base + j * 256] = residual4[base + j * 256];
    } else if (bid < 3072) {                       // x -> bf16
        size_t i = ((size_t)(bid - 1024) * 256 + t) * 8;
        const float* src = x + i;
        short8 o;
#pragma unroll
        for (int j = 0; j < 8; j++) o[j] = (short)f2bf(src[j]);
        *(short8*)(xb + i) = o;
    } else if (bid < 3840) {                       // W_QKV transpose
        int u = bid - 3072;
        const int d0 = (u & 15) * 64;
        const int h  = (u >> 4) & 15;
        const int which = u >> 8;
        const float* W = (which == 0) ? WQ : (which == 1) ? WK : WV;
        const float* src = W + (size_t)h * DD * DHD;
#pragma unroll
        for (int i = 0; i < 16; i++) {
            int idx = i * 256 + t;
            int r = idx >> 6, c = idx & 63;
            tile[r][c] = src[(size_t)(d0 + r) * DHD + c];
        }
        __syncthreads();
        unsigned short* dst = Wt + ((size_t)which * 1024 + h * 64) * DD;
#pragma unroll
        for (int i = 0; i < 16; i++) {
            int idx = i * 256 + t;
            int e = idx >> 6, d = idx & 63;
            dst[(size_t)e * DD + d0 + d] = f2bf(tile[d][e]);
        }
    } else {                                       // W_O transpose
        int u = bid - 3840;
        const int k0 = (u & 15) * 64;
        const int n0 = (u >> 4) * 64;
#pragma unroll
        for (int i = 0; i < 16; i++) {
            int idx = i * 256 + t;
            int r = idx >> 6, c = idx & 63;
            tile[r][c] = WO[(size_t)(k0 + r) * DD + n0 + c];
        }
        __syncthreads();
#pragma unroll
        for (int i = 0; i < 16; i++) {
            int idx = i * 256 + t;
            int n = idx >> 6, kk = idx & 63;
            WtO[(size_t)(n0 + n) * DD + k0 + kk] = f2bf(tile[kk][n]);
        }
    }
}

// ---------------------------------------------------------------------------
// QKV MFMA GEMM: async g2l16 staging into unpadded XOR-swizzled LDS.
// grid (32, 24); block 256 = 4 waves; wave w: M rows [w*32,w*32+32) x 128 N.
// V (which==2) stored pre-transposed [B][H][64][S] via an LDS-transpose
// epilogue with coalesced b128 stores (round-8's direct 2B scatter cost ~8us).
// ---------------------------------------------------------------------------
__global__ __launch_bounds__(256) void qkv_mfma(const unsigned short* __restrict__ xb,
        const unsigned short* __restrict__ Wt,
        const float* __restrict__ bQ, const float* __restrict__ bK,
        const float* __restrict__ bV,
        unsigned short* __restrict__ oq, unsigned short* __restrict__ ok,
        unsigned short* __restrict__ ov) {
    __shared__ unsigned short smem[128 * 132];     // >= 2*128*64; epi: 128x132
    unsigned short* As = smem;                     // 128 x 64 (unpadded)
    unsigned short* Bs = smem + 128 * 64;

    const int m0 = blockIdx.x * 128;
    const int y  = blockIdx.y;
    const int which = y >> 3;
    const int h0 = (y & 7) * 2;
    const float* bias = (which == 0) ? bQ : (which == 1) ? bK : bV;
    unsigned short* ob = (which == 0) ? oq : (which == 1) ? ok : ov;
    const float scale = (which == 0) ? 0.125f : 1.0f;
    const unsigned short* Wb = Wt + (size_t)y * 128 * DD;

    const int t = threadIdx.x;
    const int lane = t & 63, w = t >> 6;
    const int l15 = lane & 15, quad = lane >> 4;

    floatx4 acc[2][8];
#pragma unroll
    for (int mt = 0; mt < 2; mt++)
#pragma unroll
        for (int nt = 0; nt < 8; nt++) acc[mt][nt] = floatx4{0.f, 0.f, 0.f, 0.f};

    for (int k0 = 0; k0 < DD; k0 += 64) {
#pragma unroll
        for (int i = 0; i < 4; i++) {              // async stage A (swizzled src)
            int c = i * 256 + t;
            int row = c >> 3, c8 = c & 7;
            g2l16(xb + (size_t)(m0 + row) * DD + k0 + SW(row, c8) * 8, As + c * 8);
        }
#pragma unroll
        for (int i = 0; i < 4; i++) {              // async stage B
            int c = i * 256 + t;
            int row = c >> 3, c8 = c & 7;
            g2l16(Wb + (size_t)row * DD + k0 + SW(row, c8) * 8, Bs + c * 8);
        }
        __syncthreads();                            // drains vmcnt
#pragma unroll
        for (int ks = 0; ks < 2; ks++) {
            short8 af[2], bf[8];
#pragma unroll
            for (int mt = 0; mt < 2; mt++)
                af[mt] = *(const short8*)(As + (w * 32 + mt * 16 + l15) * 64 +
                                          SW(l15, ks * 4 + quad) * 8);
#pragma unroll
            for (int nt = 0; nt < 8; nt++)
                bf[nt] = *(const short8*)(Bs + (nt * 16 + l15) * 64 +
                                          SW(l15, ks * 4 + quad) * 8);
#pragma unroll
            for (int mt = 0; mt < 2; mt++)
#pragma unroll
                for (int nt = 0; nt < 8; nt++)
                    acc[mt][nt] = __builtin_amdgcn_mfma_f32_16x16x32_bf16(
                        af[mt], bf[nt], acc[mt][nt], 0, 0, 0);
        }
        __syncthreads();
    }

    if (which == 2) {
        // V: transpose block tile in LDS, store V^T [B][H][64][S] coalesced.
        unsigned short* T = smem;                  // 128(n) x 132 stride
#pragma unroll
        for (int mt = 0; mt < 2; mt++)
#pragma unroll
            for (int r = 0; r < 4; r++) {
                int mloc = w * 32 + mt * 16 + quad * 4 + r;
#pragma unroll
                for (int nt = 0; nt < 8; nt++) {
                    int n = nt * 16 + l15;
                    int h = h0 + (n >> 6), e = n & 63;
                    T[n * 132 + mloc] = f2bf(acc[mt][nt][r] + bias[h * DHD + e]);
                }
            }
        __syncthreads();
        const int b = m0 >> 11;
        const int s_base = m0 & (SS - 1);
#pragma unroll
        for (int i = 0; i < 8; i++) {
            int u = i * 256 + t;
            int row = u >> 4, c8 = u & 15;
            int h = h0 + (row >> 6), e = row & 63;
            *(short8*)(ov + (((size_t)b * HH + h) * DHD + e) * SS + s_base + c8 * 8) =
                *(const short8*)(T + row * 132 + c8 * 8);
        }
    } else {
#pragma unroll
        for (int mt = 0; mt < 2; mt++) {
#pragma unroll
            for (int r = 0; r < 4; r++) {
                int m = m0 + w * 32 + mt * 16 + quad * 4 + r;
                int b = m >> 11, s = m & (SS - 1);
#pragma unroll
                for (int nt = 0; nt < 8; nt++) {
                    int h = h0 + (nt >> 2);
                    int e = (nt & 3) * 16 + l15;
                    float v = (acc[mt][nt][r] + bias[h * DHD + e]) * scale;
                    ob[(((size_t)b * HH + h) * SS + s) * DHD + e] = f2bf(v);
                }
            }
        }
    }
}

// ---------------------------------------------------------------------------
// MFMA flash attention (unchanged from round 8): no-rescale softmax,
// Q-tile 128, K-tile 128, 512 threads = 8 waves, V^T input [B][H][64][S].
// ---------------------------------------------------------------------------
#define KSTRIDE 72
#define VSTRIDE 136
__global__ __launch_bounds__(512) void attn(const unsigned short* __restrict__ q,
        const unsigned short* __restrict__ k, const unsigned short* __restrict__ vt,
        unsigned short* __restrict__ z) {
    __shared__ unsigned short Ks[128 * KSTRIDE];
    __shared__ unsigned short Vt[64 * VSTRIDE];
    __shared__ unsigned short Ps[8 * 16 * VSTRIDE];

    const int i0 = blockIdx.x;
    int bh, qt;
    if (i0 < 256) { bh = i0 & 31;         qt = 15 - (i0 >> 5); }
    else          { bh = (i0 - 256) & 31; qt = (i0 - 256) >> 5; }
    const int b  = bh >> 4, h = bh & (HH - 1);
    const int q0 = qt * 128;

    const int t = threadIdx.x;
    const int lane = t & 63;
    const int w = t >> 6;
    const int l15 = lane & 15;
    const int quad = lane >> 4;

    const unsigned short* qb  = q  + (size_t)bh * SS * DHD;
    const unsigned short* kb  = k  + (size_t)bh * SS * DHD;
    const unsigned short* vtb = vt + (size_t)bh * DHD * SS;

    short8 a_frag[2];
#pragma unroll
    for (int c = 0; c < 2; c++)
        a_frag[c] = *(const short8*)(qb +
            (size_t)(q0 + w * 16 + l15) * DHD + c * 32 + quad * 8);

    float lsum[4];
    floatx4 o_acc[4];
#pragma unroll
    for (int r = 0; r < 4; r++) lsum[r] = 0.f;
#pragma unroll
    for (int nt = 0; nt < 4; nt++) o_acc[nt] = floatx4{0.f, 0.f, 0.f, 0.f};

    unsigned short* Psw = Ps + w * 16 * VSTRIDE;
    const int fmin = q0 + w * 16;
    const int wave_max_row = fmin + 15;
    const int nkt = qt + 1;

    for (int kt = 0; kt < nkt; kt++) {
        __syncthreads();
#pragma unroll
        for (int i = 0; i < 2; i++) {              // stage K: 128 rows x 64e
            int u = i * 512 + t;
            int row = u >> 3, c8 = u & 7;
            *(short8*)(Ks + row * KSTRIDE + c8 * 8) =
                *(const short8*)(kb + (size_t)(kt * 128 + row) * DHD + c8 * 8);
        }
#pragma unroll
        for (int i = 0; i < 2; i++) {              // stage Vt: 64 e-rows x 128kp
            int u = i * 512 + t;
            int e = u >> 4, c8 = u & 15;
            *(short8*)(Vt + e * VSTRIDE + c8 * 8) =
                *(const short8*)(vtb + (size_t)e * SS + kt * 128 + c8 * 8);
        }
        __syncthreads();

        floatx4 sacc[8];
#pragma unroll
        for (int nt = 0; nt < 8; nt++) {
            const int kb0 = kt * 128 + nt * 16;
            if (kb0 > wave_max_row) {
                sacc[nt] = floatx4{-1e30f, -1e30f, -1e30f, -1e30f};
            } else {
                short8 bf0 = *(const short8*)(Ks + (nt * 16 + l15) * KSTRIDE +
                                              quad * 8);
                short8 bf1 = *(const short8*)(Ks + (nt * 16 + l15) * KSTRIDE +
                                              32 + quad * 8);
                floatx4 acc = {0.f, 0.f, 0.f, 0.f};
                acc = __builtin_amdgcn_mfma_f32_16x16x32_bf16(a_frag[0], bf0, acc,
                                                              0, 0, 0);
                acc = __builtin_amdgcn_mfma_f32_16x16x32_bf16(a_frag[1], bf1, acc,
                                                              0, 0, 0);
                if (kb0 + 15 > fmin) {
#pragma unroll
                    for (int r = 0; r < 4; r++)
                        if (kb0 + l15 > fmin + quad * 4 + r) acc[r] = -1e30f;
                }
                sacc[nt] = acc;
            }
        }

#pragma unroll
        for (int r = 0; r < 4; r++) {
            float ps = 0.f;
#pragma unroll
            for (int nt = 0; nt < 8; nt++) {
                float pv = __expf(sacc[nt][r]);
                ps += pv;
                Psw[(quad * 4 + r) * VSTRIDE + nt * 16 + l15] = f2bf(pv);
            }
            lsum[r] += ps;
        }

        short8 pa[4];
#pragma unroll
        for (int ks = 0; ks < 4; ks++)
            pa[ks] = *(const short8*)(Psw + l15 * VSTRIDE + ks * 32 + quad * 8);
#pragma unroll
        for (int nt = 0; nt < 4; nt++) {
#pragma unroll
            for (int ks = 0; ks < 4; ks++) {
                short8 bf = *(const short8*)(Vt + (nt * 16 + l15) * VSTRIDE +
                                             ks * 32 + quad * 8);
                o_acc[nt] = __builtin_amdgcn_mfma_f32_16x16x32_bf16(
                    pa[ks], bf, o_acc[nt], 0, 0, 0);
            }
        }
    }

#pragma unroll
    for (int r = 0; r < 4; r++) {
        float s = lsum[r];
#pragma unroll
        for (int off = 1; off < 16; off <<= 1) s += __shfl_xor(s, off);
        float inv = 1.f / s;
        int qrow = q0 + w * 16 + quad * 4 + r;
        unsigned short* zr = z + ((size_t)b * SS + qrow) * (HH * DHD) + h * DHD;
#pragma unroll
        for (int nt = 0; nt < 4; nt++)
            zr[nt * 16 + l15] = f2bf(o_acc[nt][r] * inv);
    }
}

// ---------------------------------------------------------------------------
// O-proj MFMA GEMM, 64x128 tiles, async swizzled staging. grid (64, 8).
// ---------------------------------------------------------------------------
__global__ __launch_bounds__(256) void out_mfma(const unsigned short* __restrict__ zb,
        const unsigned short* __restrict__ WtO, const float* __restrict__ bo,
        float* __restrict__ out) {
    __shared__ unsigned short As[64 * 64];
    __shared__ unsigned short Bs[128 * 64];

    const int m0 = blockIdx.x * 64;
    const int n0 = blockIdx.y * 128;
    const int t = threadIdx.x;
    const int lane = t & 63, w = t >> 6;
    const int l15 = lane & 15, quad = lane >> 4;

    floatx4 acc[8];
#pragma unroll
    for (int nt = 0; nt < 8; nt++) acc[nt] = floatx4{0.f, 0.f, 0.f, 0.f};

    for (int k0 = 0; k0 < DD; k0 += 64) {
#pragma unroll
        for (int i = 0; i < 2; i++) {              // stage A: 64 x 64
            int c = i * 256 + t;
            int row = c >> 3, c8 = c & 7;
            g2l16(zb + (size_t)(m0 + row) * DD + k0 + SW(row, c8) * 8, As + c * 8);
        }
#pragma unroll
        for (int i = 0; i < 4; i++) {              // stage B: 128 x 64
            int c = i * 256 + t;
            int row = c >> 3, c8 = c & 7;
            g2l16(WtO + (size_t)(n0 + row) * DD + k0 + SW(row, c8) * 8, Bs + c * 8);
        }
        __syncthreads();
#pragma unroll
        for (int ks = 0; ks < 2; ks++) {
            short8 af = *(const short8*)(As + (w * 16 + l15) * 64 +
                                         SW(l15, ks * 4 + quad) * 8);
#pragma unroll
            for (int nt = 0; nt < 8; nt++) {
                short8 bf = *(const short8*)(Bs + (nt * 16 + l15) * 64 +
                                             SW(l15, ks * 4 + quad) * 8);
                acc[nt] = __builtin_amdgcn_mfma_f32_16x16x32_bf16(
                    af, bf, acc[nt], 0, 0, 0);
            }
        }
        __syncthreads();
    }
#pragma unroll
    for (int r = 0; r < 4; r++) {
        int m = m0 + w * 16 + quad * 4 + r;
#pragma unroll
        for (int nt = 0; nt < 8; nt++) {
            int n = n0 + nt * 16 + l15;
            out[(size_t)m * DD + n] = acc[nt][r] + bo[n];
        }
    }
}

extern "C" void kernel_launch(void* const* d_in, const int* in_sizes, int n_in,
                              void* d_out, int out_size, void* d_ws, size_t ws_size,
                              hipStream_t stream) {
    const float* residual = (const float*)d_in[0];
    const float* x   = (const float*)d_in[1];
    const float* W_Q = (const float*)d_in[2];
    const float* W_K = (const float*)d_in[3];
    const float* W_V = (const float*)d_in[4];
    const float* W_O = (const float*)d_in[5];
    const float* b_Q = (const float*)d_in[6];
    const float* b_K = (const float*)d_in[7];
    const float* b_V = (const float*)d_in[8];
    const float* b_O = (const float*)d_in[9];
    float* out = (float*)d_out;

    const size_t NE = (size_t)BB * SS * HH * DHD;
    unsigned short* xb  = (unsigned short*)d_ws;
    unsigned short* Wt  = xb + (size_t)4096 * 1024;
    unsigned short* WtO = Wt + (size_t)3072 * 1024;
    unsigned short* qb  = WtO + (size_t)1024 * 1024;
    unsigned short* kb  = qb + NE;
    unsigned short* vb  = kb + NE;          // [B][H][64][S] (pre-transposed)
    unsigned short* zb  = vb + NE;

    prep<<<4096, 256, 0, stream>>>((const float4*)residual, (float4*)out,
                                   x, xb, W_Q, W_K, W_V, Wt, W_O, WtO);

    qkv_mfma<<<dim3(32, 24), 256, 0, stream>>>(xb, Wt, b_Q, b_K, b_V, qb, kb, vb);

    attn<<<512, 512, 0, stream>>>(qb, kb, vb, zb);

    out_mfma<<<dim3(64, 8), 256, 0, stream>>>(
        zb, WtO, b_O, out + (size_t)BB * SS * DD);
}